// Round 5
// baseline (454.815 us; speedup 1.0000x reference)
//
#include <hip/hip_runtime.h>

#define NN 100000
#define NE 1600000
#define HID 128
#define KEXT 160            // padded K: 128 feat | 16 edge | deg | 1 | 14 zero
#define ROWB 320            // bytes per ext row (KEXT * 2)
#define NCPY 8              // cursor/hist privatization copies, XCD-aligned (blockIdx&7)
#define BN_EPS 1e-5f

typedef __attribute__((ext_vector_type(8))) short bf16x8;
typedef __attribute__((ext_vector_type(4))) float f32x4;

__device__ inline unsigned short f2bf(float x) {
  union { float f; unsigned u; } v; v.f = x;
  unsigned r = v.u + 0x7FFFu + ((v.u >> 16) & 1u);
  return (unsigned short)(r >> 16);
}
__device__ inline unsigned pk2(float a, float b) {
  return (unsigned)f2bf(a) | ((unsigned)f2bf(b) << 16);
}
__device__ inline float bflo(unsigned p) { return __uint_as_float(p << 16); }
__device__ inline float bfhi(unsigned p) { return __uint_as_float(p & 0xffff0000u); }
__device__ inline float bfu(unsigned short u) { return __uint_as_float((unsigned)u << 16); }

__device__ inline void gload_lds16(const void* g, void* l) {
  __builtin_amdgcn_global_load_lds((const __attribute__((address_space(1))) void*)g,
                                   (__attribute__((address_space(3))) void*)l, 16, 0, 0);
}

// ---------------- build extended bf16 weight matrices ----------------
__global__ __launch_bounds__(256) void wext_k(
    const float* __restrict__ W1, const float* __restrict__ Wb,
    const float* __restrict__ bb, const float* __restrict__ b1,
    const float* __restrict__ W2, const float* __restrict__ b2,
    unsigned short* __restrict__ W1e, unsigned short* __restrict__ W2e) {
  int idx = blockIdx.x * 256 + threadIdx.x;
  if (idx >= 128 * KEXT) return;
  int c = idx / KEXT, k = idx - c * KEXT;
  float v1 = 0.f, v2 = 0.f;
  if (k < 128) { v1 = W1[c * HID + k]; v2 = W2[c * HID + k]; }
  else if (k < 144) v1 = Wb[c * 16 + (k - 128)];
  else if (k == 144) v1 = bb[c];
  else if (k == 145) v1 = b1[c];
  if (k == 128) v2 = b2[c];
  W1e[idx] = f2bf(v1);
  W2e[idx] = f2bf(v2);
}

// ---------------- features f32 -> bf16 (packed pairs) ----------------
__global__ __launch_bounds__(256) void featbf16_k(const float* __restrict__ f,
                                                  unsigned* __restrict__ fb) {
  int i = blockIdx.x * 256 + threadIdx.x;
  if (i >= NN * HID / 2) return;
  float2 v = ((const float2*)f)[i];
  fb[i] = pk2(v.x, v.y);
}

// ---------------- degree histogram, 8-way XCD-aligned privatized ----------------
__global__ __launch_bounds__(256) void hist_k(const int* __restrict__ dst,
                                              int* __restrict__ degp) {
  int e = blockIdx.x * 256 + threadIdx.x;
  if (e < NE) atomicAdd(&degp[(blockIdx.x & (NCPY - 1)) * NN + dst[e]], 1);
}

// ---------------- scan (3-kernel) over summed copies ----------------
__global__ __launch_bounds__(1024) void scan_a(const int* __restrict__ degp,
                                               int* __restrict__ incl,
                                               int* __restrict__ bsum) {
  __shared__ int s[1024];
  int t = threadIdx.x;
  int i = blockIdx.x * 1024 + t;
  int x = 0;
  if (i < NN) {
#pragma unroll
    for (int c = 0; c < NCPY; ++c) x += degp[c * NN + i];
  }
  s[t] = x;
  __syncthreads();
  for (int off = 1; off < 1024; off <<= 1) {
    int v = (t >= off) ? s[t - off] : 0;
    __syncthreads();
    s[t] += v;
    __syncthreads();
  }
  if (i < NN) incl[i] = s[t];
  if (t == 1023) bsum[blockIdx.x] = s[1023];
}

__global__ void scan_b(const int* __restrict__ bsum, int* __restrict__ boff, int nb) {
  if (blockIdx.x == 0 && threadIdx.x == 0) {
    int run = 0;
    for (int b = 0; b < nb; ++b) { boff[b] = run; run += bsum[b]; }
  }
}

// per-copy cursor bases: cur[c][i] = row_start[i] + sum_{c'<c} h[c'][i]
__global__ __launch_bounds__(256) void scan_c(const int* __restrict__ degp,
                                              int* __restrict__ row_start,
                                              int* __restrict__ cursorp,
                                              const int* __restrict__ boff) {
  int i = blockIdx.x * 256 + threadIdx.x;
  if (i < NN) {
    int h[NCPY], tot = 0;
#pragma unroll
    for (int c = 0; c < NCPY; ++c) { h[c] = degp[c * NN + i]; tot += h[c]; }
    int v = row_start[i + 1] + boff[i >> 10];
    row_start[i + 1] = v;
    int st = v - tot;
#pragma unroll
    for (int c = 0; c < NCPY; ++c) { cursorp[c * NN + i] = st; st += h[c]; }
    if (i == 0) row_start[0] = 0;
  }
}

// ---------------- CSR fill, 64B full-line records {src, pad, ef bf16[16], pad} ----------------
__global__ __launch_bounds__(256) void fill_rec(const int* __restrict__ src,
                                                const int* __restrict__ dst,
                                                const float* __restrict__ ef,
                                                int* __restrict__ cursorp,
                                                char* __restrict__ recs) {
  int e = blockIdx.x * 256 + threadIdx.x;
  if (e >= NE) return;
  int d = dst[e];
  int p = atomicAdd(&cursorp[(blockIdx.x & (NCPY - 1)) * NN + d], 1);
  const float4* efp = (const float4*)(ef + (size_t)e * 16);
  float4 e0 = efp[0], e1 = efp[1], e2 = efp[2], e3 = efp[3];
  float4* r = (float4*)(recs + (size_t)p * 64);
  float4 w;
  w.x = __int_as_float(src[e]); w.y = 0.f;
  w.z = __uint_as_float(pk2(e0.x, e0.y)); w.w = __uint_as_float(pk2(e0.z, e0.w));
  r[0] = w;
  w.x = __uint_as_float(pk2(e1.x, e1.y)); w.y = __uint_as_float(pk2(e1.z, e1.w));
  w.z = __uint_as_float(pk2(e2.x, e2.y)); w.w = __uint_as_float(pk2(e2.z, e2.w));
  r[1] = w;
  w.x = __uint_as_float(pk2(e3.x, e3.y)); w.y = __uint_as_float(pk2(e3.z, e3.w));
  w.z = 0.f; w.w = 0.f;
  r[2] = w;
  r[3] = make_float4(0.f, 0.f, 0.f, 0.f);
}

// ---------------- merged gather: feat mailbox + ef mailbox from records ----------------
__global__ __launch_bounds__(256) void feg_k(const unsigned* __restrict__ fb,
                                             const int* __restrict__ rs,
                                             const char* __restrict__ recs,
                                             unsigned short* __restrict__ A1) {
  int wid = threadIdx.x >> 6, lane = threadIdx.x & 63;
  int node = blockIdx.x * 4 + wid;
  if (node >= NN) return;
  int start = rs[node], end = rs[node + 1];
  int l15 = lane & 15, grp = lane >> 4;
  float ax0 = 0.f, ay0 = 0.f, ax1 = 0.f, ay1 = 0.f;
  float ax2 = 0.f, ay2 = 0.f, ax3 = 0.f, ay3 = 0.f, efa = 0.f;
  int i = start;
  for (; i + 4 <= end; i += 4) {
    int sv = 0;
    if (lane < 4) sv = *(const int*)(recs + (size_t)(i + lane) * 64);
    int s0 = __shfl(sv, 0), s1 = __shfl(sv, 1), s2 = __shfl(sv, 2), s3 = __shfl(sv, 3);
    unsigned p0 = fb[s0 * 64 + lane];
    unsigned p1 = fb[s1 * 64 + lane];
    unsigned p2 = fb[s2 * 64 + lane];
    unsigned p3 = fb[s3 * 64 + lane];
    efa += bfu(*(const unsigned short*)(recs + (size_t)(i + grp) * 64 + 8 + 2 * l15));
    ax0 += bflo(p0); ay0 += bfhi(p0);
    ax1 += bflo(p1); ay1 += bfhi(p1);
    ax2 += bflo(p2); ay2 += bfhi(p2);
    ax3 += bflo(p3); ay3 += bfhi(p3);
  }
  for (; i < end; ++i) {
    int sv = 0;
    if (lane == 0) sv = *(const int*)(recs + (size_t)i * 64);
    int s0 = __shfl(sv, 0);
    unsigned p0 = fb[s0 * 64 + lane];
    ax0 += bflo(p0); ay0 += bfhi(p0);
    if (lane < 16) efa += bfu(*(const unsigned short*)(recs + (size_t)i * 64 + 8 + 2 * l15));
  }
  efa += __shfl_xor(efa, 16);
  efa += __shfl_xor(efa, 32);
  float ax = (ax0 + ax1) + (ax2 + ax3);
  float ay = (ay0 + ay1) + (ay2 + ay3);
  char* rowp = (char*)A1 + (size_t)node * ROWB;
  *(unsigned*)(rowp + lane * 4) = pk2(ax, ay);
  if (lane < 16) {
    *(unsigned short*)(rowp + 256 + 2 * l15) = f2bf(efa);
    unsigned short tail = (l15 == 0) ? f2bf((float)(end - start))
                        : (l15 == 1) ? (unsigned short)0x3F80 : (unsigned short)0;
    *(unsigned short*)(rowp + 288 + 2 * l15) = tail;
  }
}

// ---------------- fallback path (small workspace): pairs CSR ----------------
__global__ __launch_bounds__(256) void fill_pairs(const int* __restrict__ src,
                                                  const int* __restrict__ dst,
                                                  int* __restrict__ cursorp,
                                                  int2* __restrict__ pairs) {
  int e = blockIdx.x * 256 + threadIdx.x;
  if (e < NE) {
    int d = dst[e];
    int p = atomicAdd(&cursorp[(blockIdx.x & (NCPY - 1)) * NN + d], 1);
    pairs[p] = make_int2(src[e], e);
  }
}

__global__ __launch_bounds__(256) void feat_gather(const unsigned* __restrict__ fb,
                                                   const int* __restrict__ rs,
                                                   const int2* __restrict__ pairs,
                                                   unsigned short* __restrict__ A1) {
  int wid = threadIdx.x >> 6, lane = threadIdx.x & 63;
  int node = blockIdx.x * 4 + wid;
  if (node >= NN) return;
  int start = rs[node], end = rs[node + 1];
  float ax0 = 0.f, ay0 = 0.f, ax1 = 0.f, ay1 = 0.f;
  float ax2 = 0.f, ay2 = 0.f, ax3 = 0.f, ay3 = 0.f;
  int i = start;
  for (; i + 4 <= end; i += 4) {
    int s0 = pairs[i].x, s1 = pairs[i + 1].x, s2 = pairs[i + 2].x, s3 = pairs[i + 3].x;
    unsigned p0 = fb[s0 * 64 + lane];
    unsigned p1 = fb[s1 * 64 + lane];
    unsigned p2 = fb[s2 * 64 + lane];
    unsigned p3 = fb[s3 * 64 + lane];
    ax0 += bflo(p0); ay0 += bfhi(p0);
    ax1 += bflo(p1); ay1 += bfhi(p1);
    ax2 += bflo(p2); ay2 += bfhi(p2);
    ax3 += bflo(p3); ay3 += bfhi(p3);
  }
  for (; i < end; ++i) {
    unsigned p0 = fb[pairs[i].x * 64 + lane];
    ax0 += bflo(p0); ay0 += bfhi(p0);
  }
  float ax = (ax0 + ax1) + (ax2 + ax3);
  float ay = (ay0 + ay1) + (ay2 + ay3);
  *(unsigned*)((char*)A1 + (size_t)node * ROWB + lane * 4) = pk2(ax, ay);
}

__global__ __launch_bounds__(256) void ef_gather(const float* __restrict__ ef,
                                                 const int* __restrict__ rs,
                                                 const int2* __restrict__ pairs,
                                                 unsigned short* __restrict__ A1) {
  int l = threadIdx.x & 15;
  int node = blockIdx.x * 16 + (threadIdx.x >> 4);
  if (node >= NN) return;
  int start = rs[node], end = rs[node + 1];
  float a0 = 0.f, a1 = 0.f;
  int i = start;
  for (; i + 2 <= end; i += 2) {
    a0 += ef[pairs[i].y * 16 + l];
    a1 += ef[pairs[i + 1].y * 16 + l];
  }
  if (i < end) a0 += ef[pairs[i].y * 16 + l];
  float a = a0 + a1;
  char* rowp = (char*)A1 + (size_t)node * ROWB;
  *(unsigned short*)(rowp + 256 + l * 2) = f2bf(a);
  unsigned short tail = (l == 0) ? f2bf((float)(end - start))
                      : (l == 1) ? (unsigned short)0x3F80 : (unsigned short)0;
  *(unsigned short*)(rowp + 288 + l * 2) = tail;
}

// ---------------- MFMA GEMM: out[i][c] = A[i][:160] . W[c][:160] (+F) ----------------
template <bool RES>
__global__ __launch_bounds__(256) void gemm_mfma(
    const unsigned short* __restrict__ A, const unsigned short* __restrict__ W,
    const float* __restrict__ F, unsigned short* __restrict__ outb,
    float* __restrict__ ssum, float* __restrict__ ssq) {
  __shared__ __align__(16) char sA[64 * ROWB];    // 20 KB
  __shared__ __align__(16) char sW[128 * ROWB];   // 40 KB

  const int tid = threadIdx.x;
  const int wid = tid >> 6, lane = tid & 63;
  const size_t r0 = (size_t)blockIdx.x * 64;

#pragma unroll
  for (int q = 0; q < 5; ++q) {
    int s = q * 256 + tid;
    int row = (s * 3277) >> 16;        // s/20
    int c = s - row * 20;
    int csrc = (c < 16) ? (c ^ (row & 7)) : (16 + ((c - 16) ^ (row & 3)));
    gload_lds16((const char*)A + (r0 + row) * ROWB + csrc * 16,
                sA + (size_t)(q * 256 + wid * 64) * 16);
  }
#pragma unroll
  for (int q = 0; q < 10; ++q) {
    int s = q * 256 + tid;
    int row = (s * 3277) >> 16;
    int c = s - row * 20;
    int csrc = (c < 16) ? (c ^ (row & 7)) : (16 + ((c - 16) ^ (row & 3)));
    gload_lds16((const char*)W + (size_t)row * ROWB + csrc * 16,
                sW + (size_t)(q * 256 + wid * 64) * 16);
  }
  __syncthreads();

  const int l15 = lane & 15;
  const int kgr = lane >> 4;            // 0..3
  const int arow = wid * 16 + l15;

  bf16x8 afrag[5];
#pragma unroll
  for (int ks = 0; ks < 5; ++ks) {
    int creq = ks * 4 + kgr;
    int csw = (creq < 16) ? (creq ^ (arow & 7)) : (16 + ((creq - 16) ^ (arow & 3)));
    afrag[ks] = *(const bf16x8*)(sA + arow * ROWB + csw * 16);
  }

  f32x4 acc[8];
#pragma unroll
  for (int ct = 0; ct < 8; ++ct) acc[ct] = (f32x4){0.f, 0.f, 0.f, 0.f};

#pragma unroll
  for (int ct = 0; ct < 8; ++ct) {
    int brow = ct * 16 + l15;
#pragma unroll
    for (int ks = 0; ks < 5; ++ks) {
      int creq = ks * 4 + kgr;
      int csw = (creq < 16) ? (creq ^ (brow & 7)) : (16 + ((creq - 16) ^ (brow & 3)));
      bf16x8 bfrag = *(const bf16x8*)(sW + brow * ROWB + csw * 16);
      acc[ct] = __builtin_amdgcn_mfma_f32_16x16x32_bf16(afrag[ks], bfrag, acc[ct], 0, 0, 0);
    }
  }

  const size_t orow0 = r0 + wid * 16 + kgr * 4;
  float cs[8], cq[8];
#pragma unroll
  for (int ct = 0; ct < 8; ++ct) {
    int col = ct * 16 + l15;
    float s_ = 0.f, q_ = 0.f;
#pragma unroll
    for (int r = 0; r < 4; ++r) {
      size_t row = orow0 + r;
      if (row < NN) {
        float v = acc[ct][r];
        if (RES) v += F[row * HID + col];
        outb[row * HID + col] = f2bf(v);
        s_ += v; q_ += v * v;
      }
    }
    cs[ct] = s_; cq[ct] = q_;
  }

#pragma unroll
  for (int ct = 0; ct < 8; ++ct) {
    cs[ct] += __shfl_xor(cs[ct], 16); cs[ct] += __shfl_xor(cs[ct], 32);
    cq[ct] += __shfl_xor(cq[ct], 16); cq[ct] += __shfl_xor(cq[ct], 32);
  }
  __syncthreads();
  float* red = (float*)sA;
  if (lane < 16) {
#pragma unroll
    for (int ct = 0; ct < 8; ++ct) {
      red[wid * 256 + ct * 16 + l15] = cs[ct];
      red[wid * 256 + 128 + ct * 16 + l15] = cq[ct];
    }
  }
  __syncthreads();
  if (tid < 128) {
    float s_ = red[tid] + red[256 + tid] + red[512 + tid] + red[768 + tid];
    float q_ = red[128 + tid] + red[384 + tid] + red[640 + tid] + red[896 + tid];
    atomicAdd(&ssum[tid], s_);
    atomicAdd(&ssq[tid], q_);
  }
}

// ---------------- BN finalize ----------------
__global__ void bnfinal_k(const float* __restrict__ ssum, const float* __restrict__ ssq,
                          const float* __restrict__ gamma, const float* __restrict__ beta,
                          float* __restrict__ scale, float* __restrict__ shift) {
  int c = threadIdx.x;
  if (c < HID) {
    const float invN = 1.f / (float)NN;
    float m = ssum[c] * invN;
    float var = ssq[c] * invN - m * m;
    float inv = rsqrtf(var + BN_EPS);
    float sc = gamma[c] * inv;
    scale[c] = sc;
    shift[c] = beta[c] - m * sc;
  }
}

// ---------------- BN+ReLU -> next-layer bf16 A ----------------
__global__ __launch_bounds__(256) void bn_apply_bf16(const unsigned* __restrict__ t,
                                                     const float* __restrict__ scale,
                                                     const float* __restrict__ shift,
                                                     unsigned short* __restrict__ A2) {
  int wid = threadIdx.x >> 6, lane = threadIdx.x & 63;
  size_t row = (size_t)blockIdx.x * 4 + wid;
  if (row >= NN) return;
  unsigned p = t[row * 64 + lane];
  int c = lane * 2;
  float x = fmaxf(0.f, fmaf(bflo(p), scale[c], shift[c]));
  float y = fmaxf(0.f, fmaf(bfhi(p), scale[c + 1], shift[c + 1]));
  unsigned* orow = (unsigned*)((char*)A2 + row * ROWB);
  orow[lane] = pk2(x, y);
  if (lane < 16) orow[64 + lane] = (lane == 0) ? 0x3F80u : 0u;
}

// ---------------- final BN+ReLU -> f32 out ----------------
__global__ __launch_bounds__(256) void bn_final_k(const unsigned* __restrict__ t,
                                                  const float* __restrict__ scale,
                                                  const float* __restrict__ shift,
                                                  float* __restrict__ o) {
  int i = blockIdx.x * 256 + threadIdx.x;
  if (i >= NN * 64) return;
  unsigned p = t[i];
  int c = (i & 63) * 2;
  float2 v;
  v.x = fmaxf(0.f, fmaf(bflo(p), scale[c], shift[c]));
  v.y = fmaxf(0.f, fmaf(bfhi(p), scale[c + 1], shift[c + 1]));
  ((float2*)o)[i] = v;
}

extern "C" void kernel_launch(void* const* d_in, const int* in_sizes, int n_in,
                              void* d_out, int out_size, void* d_ws, size_t ws_size,
                              hipStream_t stream) {
  (void)in_sizes; (void)n_in; (void)out_size;
  const float* features   = (const float*)d_in[0];
  const float* edge_feats = (const float*)d_in[1];
  const int*   src        = (const int*)d_in[2];
  const int*   dst        = (const int*)d_in[3];
  const float* Wb         = (const float*)d_in[4];
  const float* bb         = (const float*)d_in[5];
  const float* W1         = (const float*)d_in[6];
  const float* b1         = (const float*)d_in[7];
  const float* W2         = (const float*)d_in[8];
  const float* b2         = (const float*)d_in[9];
  const float* gamma1     = (const float*)d_in[10];
  const float* beta1      = (const float*)d_in[11];
  const float* gamma2     = (const float*)d_in[12];
  const float* beta2      = (const float*)d_in[13];
  float* outp = (float*)d_out;

  char* wsb = (char*)d_ws;
  size_t off = 0;
  auto alloc = [&](size_t nbytes) -> void* {
    off = (off + 255) & ~(size_t)255;
    void* p = wsb + off;
    off += nbytes;
    return p;
  };
  int* degp      = (int*)alloc((size_t)NCPY * NN * 4);
  int* cursorp   = (int*)alloc((size_t)NCPY * NN * 4);
  int* row_start = (int*)alloc((size_t)(NN + 1) * 4);
  int* bsum      = (int*)alloc(128 * 4);
  int* boff      = (int*)alloc(128 * 4);
  unsigned* featb = (unsigned*)alloc((size_t)NN * 64 * 4);        // reused as t-buffer
  unsigned short* A1e = (unsigned short*)alloc((size_t)100032 * ROWB);
  unsigned short* W1e = (unsigned short*)alloc(128 * KEXT * 2);
  unsigned short* W2e = (unsigned short*)alloc(128 * KEXT * 2);
  float* stats   = (float*)alloc(512 * 4);
  float* scsh    = (float*)alloc(512 * 4);
  unsigned short* tbuf = (unsigned short*)featb;  // alias: featb dead after gather

  // big path: 64B-record CSR (A2e aliases records; disjoint lifetimes)
  size_t recs_need = ((off + 255) & ~(size_t)255) + (size_t)NE * 64;
  bool big = ws_size >= recs_need;
  char* recs = nullptr;
  int2* pairs = nullptr;
  unsigned short* A2e;
  if (big) {
    recs = (char*)alloc((size_t)NE * 64);
    A2e = (unsigned short*)recs;
  } else {
    pairs = (int2*)alloc((size_t)NE * 8);
    A2e = (unsigned short*)alloc((size_t)100032 * ROWB);
  }

  hipMemsetAsync(degp, 0, (size_t)NCPY * NN * 4, stream);
  hipMemsetAsync(stats, 0, 512 * 4, stream);
  hipMemsetAsync((char*)A1e + (size_t)NN * ROWB, 0, 32 * ROWB, stream);

  wext_k<<<80, 256, 0, stream>>>(W1, Wb, bb, b1, W2, b2, W1e, W2e);
  featbf16_k<<<25000, 256, 0, stream>>>(features, featb);
  hist_k<<<6250, 256, 0, stream>>>(dst, degp);
  scan_a<<<98, 1024, 0, stream>>>(degp, row_start + 1, bsum);
  scan_b<<<1, 1, 0, stream>>>(bsum, boff, 98);
  scan_c<<<391, 256, 0, stream>>>(degp, row_start, cursorp, boff);

  if (big) {
    fill_rec<<<6250, 256, 0, stream>>>(src, dst, edge_feats, cursorp, recs);
    feg_k<<<25000, 256, 0, stream>>>(featb, row_start, recs, A1e);
  } else {
    fill_pairs<<<6250, 256, 0, stream>>>(src, dst, cursorp, pairs);
    feat_gather<<<25000, 256, 0, stream>>>(featb, row_start, pairs, A1e);
    ef_gather<<<6250, 256, 0, stream>>>(edge_feats, row_start, pairs, A1e);
  }
  // zero A2e tail rows (records dead from here on in big path)
  hipMemsetAsync((char*)A2e + (size_t)NN * ROWB, 0, 32 * ROWB, stream);

  gemm_mfma<false><<<1563, 256, 0, stream>>>(A1e, W1e, nullptr, tbuf,
                                             stats, stats + 128);
  bnfinal_k<<<1, 128, 0, stream>>>(stats, stats + 128, gamma1, beta1, scsh, scsh + 128);
  bn_apply_bf16<<<25000, 256, 0, stream>>>((const unsigned*)tbuf, scsh, scsh + 128, A2e);

  gemm_mfma<true><<<1563, 256, 0, stream>>>(A2e, W2e, features, tbuf,
                                            stats + 256, stats + 384);
  bnfinal_k<<<1, 128, 0, stream>>>(stats + 256, stats + 384, gamma2, beta2,
                                   scsh + 256, scsh + 384);
  bn_final_k<<<25000, 256, 0, stream>>>((const unsigned*)tbuf, scsh + 256, scsh + 384, outp);
}

// Round 6
// 438.829 us; speedup vs baseline: 1.0364x; 1.0364x over previous
//
#include <hip/hip_runtime.h>

#define NN 100000
#define NE 1600000
#define HID 128
#define KEXT 160            // padded K: 128 feat | 16 edge | deg | 1 | 14 zero
#define ROWB 320            // bytes per ext row (KEXT * 2)
#define NCPY 8              // hist privatization copies
#define NB 782              // coarse buckets = ceil(NN/128)
#define P1B 128             // phase-1 blocks
#define EPB ((NE + P1B - 1) / P1B)
#define BN_EPS 1e-5f

typedef __attribute__((ext_vector_type(8))) short bf16x8;
typedef __attribute__((ext_vector_type(4))) float f32x4;
typedef unsigned long long u64;

__device__ inline unsigned short f2bf(float x) {
  union { float f; unsigned u; } v; v.f = x;
  unsigned r = v.u + 0x7FFFu + ((v.u >> 16) & 1u);
  return (unsigned short)(r >> 16);
}
__device__ inline unsigned pk2(float a, float b) {
  return (unsigned)f2bf(a) | ((unsigned)f2bf(b) << 16);
}
__device__ inline float bflo(unsigned p) { return __uint_as_float(p << 16); }
__device__ inline float bfhi(unsigned p) { return __uint_as_float(p & 0xffff0000u); }

__device__ inline void gload_lds16(const void* g, void* l) {
  __builtin_amdgcn_global_load_lds((const __attribute__((address_space(1))) void*)g,
                                   (__attribute__((address_space(3))) void*)l, 16, 0, 0);
}

// ---------------- build extended bf16 weight matrices ----------------
__global__ __launch_bounds__(256) void wext_k(
    const float* __restrict__ W1, const float* __restrict__ Wb,
    const float* __restrict__ bb, const float* __restrict__ b1,
    const float* __restrict__ W2, const float* __restrict__ b2,
    unsigned short* __restrict__ W1e, unsigned short* __restrict__ W2e) {
  int idx = blockIdx.x * 256 + threadIdx.x;
  if (idx >= 128 * KEXT) return;
  int c = idx / KEXT, k = idx - c * KEXT;
  float v1 = 0.f, v2 = 0.f;
  if (k < 128) { v1 = W1[c * HID + k]; v2 = W2[c * HID + k]; }
  else if (k < 144) v1 = Wb[c * 16 + (k - 128)];
  else if (k == 144) v1 = bb[c];
  else if (k == 145) v1 = b1[c];
  if (k == 128) v2 = b2[c];
  W1e[idx] = f2bf(v1);
  W2e[idx] = f2bf(v2);
}

// ---------------- features f32 -> bf16 (packed pairs) ----------------
__global__ __launch_bounds__(256) void featbf16_k(const float* __restrict__ f,
                                                  unsigned* __restrict__ fb) {
  int i = blockIdx.x * 256 + threadIdx.x;
  if (i >= NN * HID / 2) return;
  float2 v = ((const float2*)f)[i];
  fb[i] = pk2(v.x, v.y);
}

// ---------------- degree histogram, privatized ----------------
__global__ __launch_bounds__(256) void hist_k(const int* __restrict__ dst,
                                              int* __restrict__ degp) {
  int e = blockIdx.x * 256 + threadIdx.x;
  if (e < NE) atomicAdd(&degp[(blockIdx.x & (NCPY - 1)) * NN + dst[e]], 1);
}

// ---------------- scan (3-kernel) over summed copies ----------------
__global__ __launch_bounds__(1024) void scan_a(const int* __restrict__ degp,
                                               int* __restrict__ incl,
                                               int* __restrict__ bsum) {
  __shared__ int s[1024];
  int t = threadIdx.x;
  int i = blockIdx.x * 1024 + t;
  int x = 0;
  if (i < NN) {
#pragma unroll
    for (int c = 0; c < NCPY; ++c) x += degp[c * NN + i];
  }
  s[t] = x;
  __syncthreads();
  for (int off = 1; off < 1024; off <<= 1) {
    int v = (t >= off) ? s[t - off] : 0;
    __syncthreads();
    s[t] += v;
    __syncthreads();
  }
  if (i < NN) incl[i] = s[t];
  if (t == 1023) bsum[blockIdx.x] = s[1023];
}

__global__ void scan_b(const int* __restrict__ bsum, int* __restrict__ boff, int nb) {
  if (blockIdx.x == 0 && threadIdx.x == 0) {
    int run = 0;
    for (int b = 0; b < nb; ++b) { boff[b] = run; run += bsum[b]; }
  }
}

__global__ __launch_bounds__(256) void scan_c(int* __restrict__ row_start,
                                              const int* __restrict__ boff) {
  int i = blockIdx.x * 256 + threadIdx.x;
  if (i < NN) {
    row_start[i + 1] += boff[i >> 10];
    if (i == 0) row_start[0] = 0;
  }
}

// ---------------- bucket cursor init: gcur[b] = row_start[b*128] ----------------
__global__ __launch_bounds__(256) void ginit_k(const int* __restrict__ rs,
                                               int* __restrict__ gcur) {
  int b = blockIdx.x * 256 + threadIdx.x;
  if (b < NB) gcur[b] = rs[b << 7];
}

// ---------------- phase 1: partition edges into coarse buckets ----------------
// packed u64: src[0:17) | eid[17:38) | dst[38:55)
__global__ __launch_bounds__(256) void part_k(const int* __restrict__ src,
                                              const int* __restrict__ dst,
                                              int* __restrict__ gcur,
                                              u64* __restrict__ stg) {
  __shared__ int hist[NB], base[NB];
  int b0 = blockIdx.x * EPB;
  int e1 = min(b0 + EPB, NE);
  for (int i = threadIdx.x; i < NB; i += 256) hist[i] = 0;
  __syncthreads();
  for (int e = b0 + threadIdx.x; e < e1; e += 256)
    atomicAdd(&hist[dst[e] >> 7], 1);
  __syncthreads();
  for (int i = threadIdx.x; i < NB; i += 256) {
    int c = hist[i];
    base[i] = c ? atomicAdd(&gcur[i], c) : 0;
  }
  __syncthreads();
  for (int i = threadIdx.x; i < NB; i += 256) hist[i] = 0;
  __syncthreads();
  for (int e = b0 + threadIdx.x; e < e1; e += 256) {
    int d = dst[e];
    int b = d >> 7;
    int off = atomicAdd(&hist[b], 1);
    u64 pk = (u64)(unsigned)src[e] | ((u64)(unsigned)e << 17) | ((u64)(unsigned)d << 38);
    stg[base[b] + off] = pk;
  }
}

// ---------------- phase 2: within-bucket sort by node -> final CSR ----------------
__global__ __launch_bounds__(256) void bsort_k(const u64* __restrict__ stg,
                                               const int* __restrict__ rs,
                                               u64* __restrict__ fin) {
  __shared__ int cur[128];
  int b = blockIdx.x;
  int n0 = b << 7;
  int tid = threadIdx.x;
  if (tid < 128) {
    int n = n0 + tid;
    cur[tid] = (n < NN) ? rs[n] : NE;
  }
  __syncthreads();
  int s0 = rs[n0];
  int e1 = rs[min(n0 + 128, NN)];
  for (int i = s0 + tid; i < e1; i += 256) {
    u64 pk = stg[i];
    int d = (int)(pk >> 38);
    int p = atomicAdd(&cur[d - n0], 1);
    fin[p] = pk;
  }
}

// ---------------- merged gather: feat mailbox + ef mailbox ----------------
__global__ __launch_bounds__(256) void feg_k(const unsigned* __restrict__ fb,
                                             const int* __restrict__ rs,
                                             const u64* __restrict__ fin,
                                             const float* __restrict__ ef,
                                             unsigned short* __restrict__ A1) {
  int wid = threadIdx.x >> 6, lane = threadIdx.x & 63;
  int node = blockIdx.x * 4 + wid;
  if (node >= NN) return;
  int start = rs[node], end = rs[node + 1];
  int l15 = lane & 15, grp = lane >> 4;
  float ax0 = 0.f, ay0 = 0.f, ax1 = 0.f, ay1 = 0.f;
  float ax2 = 0.f, ay2 = 0.f, ax3 = 0.f, ay3 = 0.f, efa = 0.f;
  int i = start;
  for (; i + 4 <= end; i += 4) {
    int sl = 0, el = 0;
    if (lane < 4) {
      u64 pk = fin[i + lane];
      sl = (int)(pk & 0x1FFFF);
      el = (int)((pk >> 17) & 0x1FFFFF);
    }
    int s0 = __shfl(sl, 0), s1 = __shfl(sl, 1), s2 = __shfl(sl, 2), s3 = __shfl(sl, 3);
    int eg = __shfl(el, grp);
    unsigned p0 = fb[s0 * 64 + lane];
    unsigned p1 = fb[s1 * 64 + lane];
    unsigned p2 = fb[s2 * 64 + lane];
    unsigned p3 = fb[s3 * 64 + lane];
    efa += ef[(size_t)eg * 16 + l15];
    ax0 += bflo(p0); ay0 += bfhi(p0);
    ax1 += bflo(p1); ay1 += bfhi(p1);
    ax2 += bflo(p2); ay2 += bfhi(p2);
    ax3 += bflo(p3); ay3 += bfhi(p3);
  }
  for (; i < end; ++i) {
    int sl = 0, el = 0;
    if (lane == 0) {
      u64 pk = fin[i];
      sl = (int)(pk & 0x1FFFF);
      el = (int)((pk >> 17) & 0x1FFFFF);
    }
    int s0 = __shfl(sl, 0), e0 = __shfl(el, 0);
    unsigned p0 = fb[s0 * 64 + lane];
    ax0 += bflo(p0); ay0 += bfhi(p0);
    if (lane < 16) efa += ef[(size_t)e0 * 16 + l15];
  }
  efa += __shfl_xor(efa, 16);
  efa += __shfl_xor(efa, 32);
  float ax = (ax0 + ax1) + (ax2 + ax3);
  float ay = (ay0 + ay1) + (ay2 + ay3);
  char* rowp = (char*)A1 + (size_t)node * ROWB;
  *(unsigned*)(rowp + lane * 4) = pk2(ax, ay);
  if (lane < 16) {
    *(unsigned short*)(rowp + 256 + 2 * l15) = f2bf(efa);
    unsigned short tail = (l15 == 0) ? f2bf((float)(end - start))
                        : (l15 == 1) ? (unsigned short)0x3F80 : (unsigned short)0;
    *(unsigned short*)(rowp + 288 + 2 * l15) = tail;
  }
}

// ---------------- MFMA GEMM: out[i][c] = A[i][:160] . W[c][:160] (+F) ----------------
template <bool RES>
__global__ __launch_bounds__(256) void gemm_mfma(
    const unsigned short* __restrict__ A, const unsigned short* __restrict__ W,
    const float* __restrict__ F, unsigned short* __restrict__ outb,
    float* __restrict__ ssum, float* __restrict__ ssq) {
  __shared__ __align__(16) char sA[64 * ROWB];    // 20 KB
  __shared__ __align__(16) char sW[128 * ROWB];   // 40 KB

  const int tid = threadIdx.x;
  const int wid = tid >> 6, lane = tid & 63;
  const size_t r0 = (size_t)blockIdx.x * 64;

#pragma unroll
  for (int q = 0; q < 5; ++q) {
    int s = q * 256 + tid;
    int row = (s * 3277) >> 16;        // s/20
    int c = s - row * 20;
    int csrc = (c < 16) ? (c ^ (row & 7)) : (16 + ((c - 16) ^ (row & 3)));
    gload_lds16((const char*)A + (r0 + row) * ROWB + csrc * 16,
                sA + (size_t)(q * 256 + wid * 64) * 16);
  }
#pragma unroll
  for (int q = 0; q < 10; ++q) {
    int s = q * 256 + tid;
    int row = (s * 3277) >> 16;
    int c = s - row * 20;
    int csrc = (c < 16) ? (c ^ (row & 7)) : (16 + ((c - 16) ^ (row & 3)));
    gload_lds16((const char*)W + (size_t)row * ROWB + csrc * 16,
                sW + (size_t)(q * 256 + wid * 64) * 16);
  }
  __syncthreads();

  const int l15 = lane & 15;
  const int kgr = lane >> 4;            // 0..3
  const int arow = wid * 16 + l15;

  bf16x8 afrag[5];
#pragma unroll
  for (int ks = 0; ks < 5; ++ks) {
    int creq = ks * 4 + kgr;
    int csw = (creq < 16) ? (creq ^ (arow & 7)) : (16 + ((creq - 16) ^ (arow & 3)));
    afrag[ks] = *(const bf16x8*)(sA + arow * ROWB + csw * 16);
  }

  f32x4 acc[8];
#pragma unroll
  for (int ct = 0; ct < 8; ++ct) acc[ct] = (f32x4){0.f, 0.f, 0.f, 0.f};

#pragma unroll
  for (int ct = 0; ct < 8; ++ct) {
    int brow = ct * 16 + l15;
#pragma unroll
    for (int ks = 0; ks < 5; ++ks) {
      int creq = ks * 4 + kgr;
      int csw = (creq < 16) ? (creq ^ (brow & 7)) : (16 + ((creq - 16) ^ (brow & 3)));
      bf16x8 bfrag = *(const bf16x8*)(sW + brow * ROWB + csw * 16);
      acc[ct] = __builtin_amdgcn_mfma_f32_16x16x32_bf16(afrag[ks], bfrag, acc[ct], 0, 0, 0);
    }
  }

  const size_t orow0 = r0 + wid * 16 + kgr * 4;
  float cs[8], cq[8];
#pragma unroll
  for (int ct = 0; ct < 8; ++ct) {
    int col = ct * 16 + l15;
    float s_ = 0.f, q_ = 0.f;
#pragma unroll
    for (int r = 0; r < 4; ++r) {
      size_t row = orow0 + r;
      if (row < NN) {
        float v = acc[ct][r];
        if (RES) v += F[row * HID + col];
        outb[row * HID + col] = f2bf(v);
        s_ += v; q_ += v * v;
      }
    }
    cs[ct] = s_; cq[ct] = q_;
  }

#pragma unroll
  for (int ct = 0; ct < 8; ++ct) {
    cs[ct] += __shfl_xor(cs[ct], 16); cs[ct] += __shfl_xor(cs[ct], 32);
    cq[ct] += __shfl_xor(cq[ct], 16); cq[ct] += __shfl_xor(cq[ct], 32);
  }
  __syncthreads();
  float* red = (float*)sA;
  if (lane < 16) {
#pragma unroll
    for (int ct = 0; ct < 8; ++ct) {
      red[wid * 256 + ct * 16 + l15] = cs[ct];
      red[wid * 256 + 128 + ct * 16 + l15] = cq[ct];
    }
  }
  __syncthreads();
  if (tid < 128) {
    float s_ = red[tid] + red[256 + tid] + red[512 + tid] + red[768 + tid];
    float q_ = red[128 + tid] + red[384 + tid] + red[640 + tid] + red[896 + tid];
    atomicAdd(&ssum[tid], s_);
    atomicAdd(&ssq[tid], q_);
  }
}

// ---------------- BN finalize ----------------
__global__ void bnfinal_k(const float* __restrict__ ssum, const float* __restrict__ ssq,
                          const float* __restrict__ gamma, const float* __restrict__ beta,
                          float* __restrict__ scale, float* __restrict__ shift) {
  int c = threadIdx.x;
  if (c < HID) {
    const float invN = 1.f / (float)NN;
    float m = ssum[c] * invN;
    float var = ssq[c] * invN - m * m;
    float inv = rsqrtf(var + BN_EPS);
    float sc = gamma[c] * inv;
    scale[c] = sc;
    shift[c] = beta[c] - m * sc;
  }
}

// ---------------- BN+ReLU -> next-layer bf16 A ----------------
__global__ __launch_bounds__(256) void bn_apply_bf16(const unsigned* __restrict__ t,
                                                     const float* __restrict__ scale,
                                                     const float* __restrict__ shift,
                                                     unsigned short* __restrict__ A2) {
  int wid = threadIdx.x >> 6, lane = threadIdx.x & 63;
  size_t row = (size_t)blockIdx.x * 4 + wid;
  if (row >= NN) return;
  unsigned p = t[row * 64 + lane];
  int c = lane * 2;
  float x = fmaxf(0.f, fmaf(bflo(p), scale[c], shift[c]));
  float y = fmaxf(0.f, fmaf(bfhi(p), scale[c + 1], shift[c + 1]));
  unsigned* orow = (unsigned*)((char*)A2 + row * ROWB);
  orow[lane] = pk2(x, y);
  if (lane < 16) orow[64 + lane] = (lane == 0) ? 0x3F80u : 0u;
}

// ---------------- final BN+ReLU -> f32 out ----------------
__global__ __launch_bounds__(256) void bn_final_k(const unsigned* __restrict__ t,
                                                  const float* __restrict__ scale,
                                                  const float* __restrict__ shift,
                                                  float* __restrict__ o) {
  int i = blockIdx.x * 256 + threadIdx.x;
  if (i >= NN * 64) return;
  unsigned p = t[i];
  int c = (i & 63) * 2;
  float2 v;
  v.x = fmaxf(0.f, fmaf(bflo(p), scale[c], shift[c]));
  v.y = fmaxf(0.f, fmaf(bfhi(p), scale[c + 1], shift[c + 1]));
  ((float2*)o)[i] = v;
}

extern "C" void kernel_launch(void* const* d_in, const int* in_sizes, int n_in,
                              void* d_out, int out_size, void* d_ws, size_t ws_size,
                              hipStream_t stream) {
  (void)in_sizes; (void)n_in; (void)out_size; (void)ws_size;
  const float* features   = (const float*)d_in[0];
  const float* edge_feats = (const float*)d_in[1];
  const int*   src        = (const int*)d_in[2];
  const int*   dst        = (const int*)d_in[3];
  const float* Wb         = (const float*)d_in[4];
  const float* bb         = (const float*)d_in[5];
  const float* W1         = (const float*)d_in[6];
  const float* b1         = (const float*)d_in[7];
  const float* W2         = (const float*)d_in[8];
  const float* b2         = (const float*)d_in[9];
  const float* gamma1     = (const float*)d_in[10];
  const float* beta1      = (const float*)d_in[11];
  const float* gamma2     = (const float*)d_in[12];
  const float* beta2      = (const float*)d_in[13];
  float* outp = (float*)d_out;

  char* wsb = (char*)d_ws;
  size_t off = 0;
  auto alloc = [&](size_t nbytes) -> void* {
    off = (off + 255) & ~(size_t)255;
    void* p = wsb + off;
    off += nbytes;
    return p;
  };
  int* degp      = (int*)alloc((size_t)NCPY * NN * 4);
  int* row_start = (int*)alloc((size_t)(NN + 1) * 4);
  int* bsum      = (int*)alloc(128 * 4);
  int* boff      = (int*)alloc(128 * 4);
  int* gcur      = (int*)alloc(NB * 4);
  unsigned* featb = (unsigned*)alloc((size_t)NN * 64 * 4);        // reused as t-buffer
  unsigned short* A1e = (unsigned short*)alloc((size_t)100032 * ROWB);
  unsigned short* A2e = (unsigned short*)alloc((size_t)100032 * ROWB);
  unsigned short* W1e = (unsigned short*)alloc(128 * KEXT * 2);
  unsigned short* W2e = (unsigned short*)alloc(128 * KEXT * 2);
  float* stats   = (float*)alloc(512 * 4);
  float* scsh    = (float*)alloc(512 * 4);
  u64* stg       = (u64*)alloc((size_t)NE * 8);
  u64* fin       = (u64*)alloc((size_t)NE * 8);
  unsigned short* tbuf = (unsigned short*)featb;  // alias: featb dead after feg

  hipMemsetAsync(degp, 0, (size_t)NCPY * NN * 4, stream);
  hipMemsetAsync(stats, 0, 512 * 4, stream);
  hipMemsetAsync((char*)A1e + (size_t)NN * ROWB, 0, 32 * ROWB, stream);
  hipMemsetAsync((char*)A2e + (size_t)NN * ROWB, 0, 32 * ROWB, stream);

  wext_k<<<80, 256, 0, stream>>>(W1, Wb, bb, b1, W2, b2, W1e, W2e);
  featbf16_k<<<25000, 256, 0, stream>>>(features, featb);
  hist_k<<<6250, 256, 0, stream>>>(dst, degp);
  scan_a<<<98, 1024, 0, stream>>>(degp, row_start + 1, bsum);
  scan_b<<<1, 1, 0, stream>>>(bsum, boff, 98);
  scan_c<<<391, 256, 0, stream>>>(row_start, boff);
  ginit_k<<<4, 256, 0, stream>>>(row_start, gcur);
  part_k<<<P1B, 256, 0, stream>>>(src, dst, gcur, stg);
  bsort_k<<<NB, 256, 0, stream>>>(stg, row_start, fin);
  feg_k<<<25000, 256, 0, stream>>>(featb, row_start, fin, edge_feats, A1e);

  gemm_mfma<false><<<1563, 256, 0, stream>>>(A1e, W1e, nullptr, tbuf,
                                             stats, stats + 128);
  bnfinal_k<<<1, 128, 0, stream>>>(stats, stats + 128, gamma1, beta1, scsh, scsh + 128);
  bn_apply_bf16<<<25000, 256, 0, stream>>>((const unsigned*)tbuf, scsh, scsh + 128, A2e);

  gemm_mfma<true><<<1563, 256, 0, stream>>>(A2e, W2e, features, tbuf,
                                            stats + 256, stats + 384);
  bnfinal_k<<<1, 128, 0, stream>>>(stats + 256, stats + 384, gamma2, beta2,
                                   scsh + 256, scsh + 384);
  bn_final_k<<<25000, 256, 0, stream>>>((const unsigned*)tbuf, scsh + 256, scsh + 384, outp);
}

// Round 7
// 374.421 us; speedup vs baseline: 1.2147x; 1.1720x over previous
//
#include <hip/hip_runtime.h>

#define NN 100000
#define NE 1600000
#define HID 128
#define KEXT 160            // padded K: 128 feat | 16 edge | deg | 1 | 14 zero
#define ROWB 320            // bytes per ext row (KEXT * 2)
#define NB 782              // coarse buckets = ceil(NN/128)
#define P1B 128             // phase-1 blocks
#define EPB ((NE + P1B - 1) / P1B)
#define BN_EPS 1e-5f

typedef __attribute__((ext_vector_type(8))) short bf16x8;
typedef __attribute__((ext_vector_type(4))) float f32x4;
typedef unsigned long long u64;

__device__ inline unsigned short f2bf(float x) {
  union { float f; unsigned u; } v; v.f = x;
  unsigned r = v.u + 0x7FFFu + ((v.u >> 16) & 1u);
  return (unsigned short)(r >> 16);
}
__device__ inline unsigned pk2(float a, float b) {
  return (unsigned)f2bf(a) | ((unsigned)f2bf(b) << 16);
}
__device__ inline float bflo(unsigned p) { return __uint_as_float(p << 16); }
__device__ inline float bfhi(unsigned p) { return __uint_as_float(p & 0xffff0000u); }

__device__ inline void gload_lds16(const void* g, void* l) {
  __builtin_amdgcn_global_load_lds((const __attribute__((address_space(1))) void*)g,
                                   (__attribute__((address_space(3))) void*)l, 16, 0, 0);
}

// ---------------- build extended bf16 weight matrices ----------------
__global__ __launch_bounds__(256) void wext_k(
    const float* __restrict__ W1, const float* __restrict__ Wb,
    const float* __restrict__ bb, const float* __restrict__ b1,
    const float* __restrict__ W2, const float* __restrict__ b2,
    unsigned short* __restrict__ W1e, unsigned short* __restrict__ W2e) {
  int idx = blockIdx.x * 256 + threadIdx.x;
  if (idx >= 128 * KEXT) return;
  int c = idx / KEXT, k = idx - c * KEXT;
  float v1 = 0.f, v2 = 0.f;
  if (k < 128) { v1 = W1[c * HID + k]; v2 = W2[c * HID + k]; }
  else if (k < 144) v1 = Wb[c * 16 + (k - 128)];
  else if (k == 144) v1 = bb[c];
  else if (k == 145) v1 = b1[c];
  if (k == 128) v2 = b2[c];
  W1e[idx] = f2bf(v1);
  W2e[idx] = f2bf(v2);
}

// ---------------- features f32 -> bf16 (packed pairs) ----------------
__global__ __launch_bounds__(256) void featbf16_k(const float* __restrict__ f,
                                                  unsigned* __restrict__ fb) {
  int i = blockIdx.x * 256 + threadIdx.x;
  if (i >= NN * HID / 2) return;
  float2 v = ((const float2*)f)[i];
  fb[i] = pk2(v.x, v.y);
}

// ---------------- bucket-level histogram (782 buckets) ----------------
__global__ __launch_bounds__(256) void bhist_k(const int* __restrict__ dst,
                                               int* __restrict__ bcnt) {
  __shared__ int bh[NB];
  int b0 = blockIdx.x * EPB, e1 = min(b0 + EPB, NE);
  for (int i = threadIdx.x; i < NB; i += 256) bh[i] = 0;
  __syncthreads();
  for (int e = b0 + threadIdx.x; e < e1; e += 256) atomicAdd(&bh[dst[e] >> 7], 1);
  __syncthreads();
  for (int i = threadIdx.x; i < NB; i += 256)
    if (bh[i]) atomicAdd(&bcnt[i], bh[i]);
}

// ---------------- bucket scan (single block) ----------------
__global__ __launch_bounds__(1024) void bscan_k(const int* __restrict__ bcnt,
                                                int* __restrict__ bbase,
                                                int* __restrict__ gcur,
                                                int* __restrict__ rs) {
  __shared__ int s[1024];
  int t = threadIdx.x;
  int x = (t < NB) ? bcnt[t] : 0;
  s[t] = x;
  __syncthreads();
  for (int off = 1; off < 1024; off <<= 1) {
    int v = (t >= off) ? s[t - off] : 0;
    __syncthreads();
    s[t] += v;
    __syncthreads();
  }
  if (t < NB) {
    int excl = s[t] - x;
    bbase[t] = excl;
    gcur[t] = excl;
  }
  if (t == NB - 1) bbase[NB] = s[t];
  if (t == 0) rs[NN] = NE;
}

// ---------------- phase 1: partition edges into coarse buckets ----------------
// packed u64: src[0:17) | eid[17:38) | dst[38:55)
__global__ __launch_bounds__(256) void part_k(const int* __restrict__ src,
                                              const int* __restrict__ dst,
                                              int* __restrict__ gcur,
                                              u64* __restrict__ stg) {
  __shared__ int hist[NB], base[NB];
  int b0 = blockIdx.x * EPB;
  int e1 = min(b0 + EPB, NE);
  for (int i = threadIdx.x; i < NB; i += 256) hist[i] = 0;
  __syncthreads();
  for (int e = b0 + threadIdx.x; e < e1; e += 256)
    atomicAdd(&hist[dst[e] >> 7], 1);
  __syncthreads();
  for (int i = threadIdx.x; i < NB; i += 256) {
    int c = hist[i];
    base[i] = c ? atomicAdd(&gcur[i], c) : 0;
  }
  __syncthreads();
  for (int i = threadIdx.x; i < NB; i += 256) hist[i] = 0;
  __syncthreads();
  for (int e = b0 + threadIdx.x; e < e1; e += 256) {
    int d = dst[e];
    int b = d >> 7;
    int off = atomicAdd(&hist[b], 1);
    u64 pk = (u64)(unsigned)src[e] | ((u64)(unsigned)e << 17) | ((u64)(unsigned)d << 38);
    stg[base[b] + off] = pk;
  }
}

// ---------------- phase 2: in-bucket node sort; derives row_start in-LDS ----------------
__global__ __launch_bounds__(256) void bsort_k(const u64* __restrict__ stg,
                                               const int* __restrict__ bbase,
                                               int* __restrict__ rs,
                                               u64* __restrict__ fin) {
  __shared__ int h[128], cur[128], sc[128];
  int b = blockIdx.x, n0 = b << 7, tid = threadIdx.x;
  int s0 = bbase[b], e1 = bbase[b + 1];
  if (tid < 128) h[tid] = 0;
  __syncthreads();
  for (int i = s0 + tid; i < e1; i += 256)
    atomicAdd(&h[(int)(stg[i] >> 38) & 127], 1);
  __syncthreads();
  if (tid < 128) sc[tid] = h[tid];
  __syncthreads();
  for (int off = 1; off < 128; off <<= 1) {
    int v = 0;
    if (tid < 128 && tid >= off) v = sc[tid - off];
    __syncthreads();
    if (tid < 128) sc[tid] += v;
    __syncthreads();
  }
  if (tid < 128) {
    int excl = sc[tid] - h[tid];
    cur[tid] = s0 + excl;
    int n = n0 + tid;
    if (n < NN) rs[n] = s0 + excl;
  }
  __syncthreads();
  for (int i = s0 + tid; i < e1; i += 256) {
    u64 pk = stg[i];
    int d = (int)(pk >> 38) & 127;
    int p = atomicAdd(&cur[d], 1);
    fin[p] = pk;
  }
}

// ---------------- merged gather: feat mailbox + ef mailbox (8-wide ILP) ----------------
__global__ __launch_bounds__(256) void feg_k(const unsigned* __restrict__ fb,
                                             const int* __restrict__ rs,
                                             const u64* __restrict__ fin,
                                             const float* __restrict__ ef,
                                             unsigned short* __restrict__ A1) {
  int wid = threadIdx.x >> 6, lane = threadIdx.x & 63;
  int node = blockIdx.x * 4 + wid;
  if (node >= NN) return;
  int start = rs[node], end = rs[node + 1];
  int l15 = lane & 15, grp = lane >> 4;
  float ax0 = 0.f, ay0 = 0.f, ax1 = 0.f, ay1 = 0.f;
  float ax2 = 0.f, ay2 = 0.f, ax3 = 0.f, ay3 = 0.f;
  float ax4 = 0.f, ay4 = 0.f, ax5 = 0.f, ay5 = 0.f;
  float ax6 = 0.f, ay6 = 0.f, ax7 = 0.f, ay7 = 0.f;
  float efa = 0.f, efb = 0.f;
  int i = start;
  for (; i + 8 <= end; i += 8) {
    int sl = 0, el = 0;
    if (lane < 8) {
      u64 pk = fin[i + lane];
      sl = (int)(pk & 0x1FFFF);
      el = (int)((pk >> 17) & 0x1FFFFF);
    }
    int s0 = __shfl(sl, 0), s1 = __shfl(sl, 1), s2 = __shfl(sl, 2), s3 = __shfl(sl, 3);
    int s4 = __shfl(sl, 4), s5 = __shfl(sl, 5), s6 = __shfl(sl, 6), s7 = __shfl(sl, 7);
    int ega = __shfl(el, grp), egb = __shfl(el, grp + 4);
    unsigned p0 = fb[s0 * 64 + lane];
    unsigned p1 = fb[s1 * 64 + lane];
    unsigned p2 = fb[s2 * 64 + lane];
    unsigned p3 = fb[s3 * 64 + lane];
    unsigned p4 = fb[s4 * 64 + lane];
    unsigned p5 = fb[s5 * 64 + lane];
    unsigned p6 = fb[s6 * 64 + lane];
    unsigned p7 = fb[s7 * 64 + lane];
    efa += ef[(size_t)ega * 16 + l15];
    efb += ef[(size_t)egb * 16 + l15];
    ax0 += bflo(p0); ay0 += bfhi(p0);
    ax1 += bflo(p1); ay1 += bfhi(p1);
    ax2 += bflo(p2); ay2 += bfhi(p2);
    ax3 += bflo(p3); ay3 += bfhi(p3);
    ax4 += bflo(p4); ay4 += bfhi(p4);
    ax5 += bflo(p5); ay5 += bfhi(p5);
    ax6 += bflo(p6); ay6 += bfhi(p6);
    ax7 += bflo(p7); ay7 += bfhi(p7);
  }
  for (; i + 4 <= end; i += 4) {
    int sl = 0, el = 0;
    if (lane < 4) {
      u64 pk = fin[i + lane];
      sl = (int)(pk & 0x1FFFF);
      el = (int)((pk >> 17) & 0x1FFFFF);
    }
    int s0 = __shfl(sl, 0), s1 = __shfl(sl, 1), s2 = __shfl(sl, 2), s3 = __shfl(sl, 3);
    int ega = __shfl(el, grp);
    unsigned p0 = fb[s0 * 64 + lane];
    unsigned p1 = fb[s1 * 64 + lane];
    unsigned p2 = fb[s2 * 64 + lane];
    unsigned p3 = fb[s3 * 64 + lane];
    efa += ef[(size_t)ega * 16 + l15];
    ax0 += bflo(p0); ay0 += bfhi(p0);
    ax1 += bflo(p1); ay1 += bfhi(p1);
    ax2 += bflo(p2); ay2 += bfhi(p2);
    ax3 += bflo(p3); ay3 += bfhi(p3);
  }
  for (; i < end; ++i) {
    int sl = 0, el = 0;
    if (lane == 0) {
      u64 pk = fin[i];
      sl = (int)(pk & 0x1FFFF);
      el = (int)((pk >> 17) & 0x1FFFFF);
    }
    int s0 = __shfl(sl, 0), e0 = __shfl(el, 0);
    unsigned p0 = fb[s0 * 64 + lane];
    ax0 += bflo(p0); ay0 += bfhi(p0);
    if (lane < 16) efa += ef[(size_t)e0 * 16 + l15];
  }
  float efs = efa + efb;
  efs += __shfl_xor(efs, 16);
  efs += __shfl_xor(efs, 32);
  float ax = ((ax0 + ax1) + (ax2 + ax3)) + ((ax4 + ax5) + (ax6 + ax7));
  float ay = ((ay0 + ay1) + (ay2 + ay3)) + ((ay4 + ay5) + (ay6 + ay7));
  char* rowp = (char*)A1 + (size_t)node * ROWB;
  *(unsigned*)(rowp + lane * 4) = pk2(ax, ay);
  if (lane < 16) {
    *(unsigned short*)(rowp + 256 + 2 * l15) = f2bf(efs);
    unsigned short tail = (l15 == 0) ? f2bf((float)(end - start))
                        : (l15 == 1) ? (unsigned short)0x3F80 : (unsigned short)0;
    *(unsigned short*)(rowp + 288 + 2 * l15) = tail;
  }
}

// ---------------- MFMA GEMM: out[i][c] = A[i][:160] . W[c][:160] (+F) ----------------
template <bool RES>
__global__ __launch_bounds__(256) void gemm_mfma(
    const unsigned short* __restrict__ A, const unsigned short* __restrict__ W,
    const float* __restrict__ F, unsigned short* __restrict__ outb,
    float* __restrict__ ssum, float* __restrict__ ssq) {
  __shared__ __align__(16) char sA[64 * ROWB];    // 20 KB
  __shared__ __align__(16) char sW[128 * ROWB];   // 40 KB

  const int tid = threadIdx.x;
  const int wid = tid >> 6, lane = tid & 63;
  const size_t r0 = (size_t)blockIdx.x * 64;

#pragma unroll
  for (int q = 0; q < 5; ++q) {
    int s = q * 256 + tid;
    int row = (s * 3277) >> 16;        // s/20
    int c = s - row * 20;
    int csrc = (c < 16) ? (c ^ (row & 7)) : (16 + ((c - 16) ^ (row & 3)));
    gload_lds16((const char*)A + (r0 + row) * ROWB + csrc * 16,
                sA + (size_t)(q * 256 + wid * 64) * 16);
  }
#pragma unroll
  for (int q = 0; q < 10; ++q) {
    int s = q * 256 + tid;
    int row = (s * 3277) >> 16;
    int c = s - row * 20;
    int csrc = (c < 16) ? (c ^ (row & 7)) : (16 + ((c - 16) ^ (row & 3)));
    gload_lds16((const char*)W + (size_t)row * ROWB + csrc * 16,
                sW + (size_t)(q * 256 + wid * 64) * 16);
  }
  __syncthreads();

  const int l15 = lane & 15;
  const int kgr = lane >> 4;            // 0..3
  const int arow = wid * 16 + l15;

  bf16x8 afrag[5];
#pragma unroll
  for (int ks = 0; ks < 5; ++ks) {
    int creq = ks * 4 + kgr;
    int csw = (creq < 16) ? (creq ^ (arow & 7)) : (16 + ((creq - 16) ^ (arow & 3)));
    afrag[ks] = *(const bf16x8*)(sA + arow * ROWB + csw * 16);
  }

  f32x4 acc[8];
#pragma unroll
  for (int ct = 0; ct < 8; ++ct) acc[ct] = (f32x4){0.f, 0.f, 0.f, 0.f};

#pragma unroll
  for (int ct = 0; ct < 8; ++ct) {
    int brow = ct * 16 + l15;
#pragma unroll
    for (int ks = 0; ks < 5; ++ks) {
      int creq = ks * 4 + kgr;
      int csw = (creq < 16) ? (creq ^ (brow & 7)) : (16 + ((creq - 16) ^ (brow & 3)));
      bf16x8 bfrag = *(const bf16x8*)(sW + brow * ROWB + csw * 16);
      acc[ct] = __builtin_amdgcn_mfma_f32_16x16x32_bf16(afrag[ks], bfrag, acc[ct], 0, 0, 0);
    }
  }

  const size_t orow0 = r0 + wid * 16 + kgr * 4;
  float cs[8], cq[8];
#pragma unroll
  for (int ct = 0; ct < 8; ++ct) {
    int col = ct * 16 + l15;
    float s_ = 0.f, q_ = 0.f;
#pragma unroll
    for (int r = 0; r < 4; ++r) {
      size_t row = orow0 + r;
      if (row < NN) {
        float v = acc[ct][r];
        if (RES) v += F[row * HID + col];
        outb[row * HID + col] = f2bf(v);
        s_ += v; q_ += v * v;
      }
    }
    cs[ct] = s_; cq[ct] = q_;
  }

#pragma unroll
  for (int ct = 0; ct < 8; ++ct) {
    cs[ct] += __shfl_xor(cs[ct], 16); cs[ct] += __shfl_xor(cs[ct], 32);
    cq[ct] += __shfl_xor(cq[ct], 16); cq[ct] += __shfl_xor(cq[ct], 32);
  }
  __syncthreads();
  float* red = (float*)sA;
  if (lane < 16) {
#pragma unroll
    for (int ct = 0; ct < 8; ++ct) {
      red[wid * 256 + ct * 16 + l15] = cs[ct];
      red[wid * 256 + 128 + ct * 16 + l15] = cq[ct];
    }
  }
  __syncthreads();
  if (tid < 128) {
    float s_ = red[tid] + red[256 + tid] + red[512 + tid] + red[768 + tid];
    float q_ = red[128 + tid] + red[384 + tid] + red[640 + tid] + red[896 + tid];
    atomicAdd(&ssum[tid], s_);
    atomicAdd(&ssq[tid], q_);
  }
}

// ---------------- BN finalize ----------------
__global__ void bnfinal_k(const float* __restrict__ ssum, const float* __restrict__ ssq,
                          const float* __restrict__ gamma, const float* __restrict__ beta,
                          float* __restrict__ scale, float* __restrict__ shift) {
  int c = threadIdx.x;
  if (c < HID) {
    const float invN = 1.f / (float)NN;
    float m = ssum[c] * invN;
    float var = ssq[c] * invN - m * m;
    float inv = rsqrtf(var + BN_EPS);
    float sc = gamma[c] * inv;
    scale[c] = sc;
    shift[c] = beta[c] - m * sc;
  }
}

// ---------------- BN+ReLU -> next-layer bf16 A ----------------
__global__ __launch_bounds__(256) void bn_apply_bf16(const unsigned* __restrict__ t,
                                                     const float* __restrict__ scale,
                                                     const float* __restrict__ shift,
                                                     unsigned short* __restrict__ A2) {
  int wid = threadIdx.x >> 6, lane = threadIdx.x & 63;
  size_t row = (size_t)blockIdx.x * 4 + wid;
  if (row >= NN) return;
  unsigned p = t[row * 64 + lane];
  int c = lane * 2;
  float x = fmaxf(0.f, fmaf(bflo(p), scale[c], shift[c]));
  float y = fmaxf(0.f, fmaf(bfhi(p), scale[c + 1], shift[c + 1]));
  unsigned* orow = (unsigned*)((char*)A2 + row * ROWB);
  orow[lane] = pk2(x, y);
  if (lane < 16) orow[64 + lane] = (lane == 0) ? 0x3F80u : 0u;
}

// ---------------- final BN+ReLU -> f32 out ----------------
__global__ __launch_bounds__(256) void bn_final_k(const unsigned* __restrict__ t,
                                                  const float* __restrict__ scale,
                                                  const float* __restrict__ shift,
                                                  float* __restrict__ o) {
  int i = blockIdx.x * 256 + threadIdx.x;
  if (i >= NN * 64) return;
  unsigned p = t[i];
  int c = (i & 63) * 2;
  float2 v;
  v.x = fmaxf(0.f, fmaf(bflo(p), scale[c], shift[c]));
  v.y = fmaxf(0.f, fmaf(bfhi(p), scale[c + 1], shift[c + 1]));
  ((float2*)o)[i] = v;
}

extern "C" void kernel_launch(void* const* d_in, const int* in_sizes, int n_in,
                              void* d_out, int out_size, void* d_ws, size_t ws_size,
                              hipStream_t stream) {
  (void)in_sizes; (void)n_in; (void)out_size; (void)ws_size;
  const float* features   = (const float*)d_in[0];
  const float* edge_feats = (const float*)d_in[1];
  const int*   src        = (const int*)d_in[2];
  const int*   dst        = (const int*)d_in[3];
  const float* Wb         = (const float*)d_in[4];
  const float* bb         = (const float*)d_in[5];
  const float* W1         = (const float*)d_in[6];
  const float* b1         = (const float*)d_in[7];
  const float* W2         = (const float*)d_in[8];
  const float* b2         = (const float*)d_in[9];
  const float* gamma1     = (const float*)d_in[10];
  const float* beta1      = (const float*)d_in[11];
  const float* gamma2     = (const float*)d_in[12];
  const float* beta2      = (const float*)d_in[13];
  float* outp = (float*)d_out;

  char* wsb = (char*)d_ws;
  size_t off = 0;
  auto alloc = [&](size_t nbytes) -> void* {
    off = (off + 255) & ~(size_t)255;
    void* p = wsb + off;
    off += nbytes;
    return p;
  };
  int* row_start = (int*)alloc((size_t)(NN + 1) * 4);
  int* bcnt      = (int*)alloc(NB * 4);
  int* bbase     = (int*)alloc((NB + 1) * 4);
  int* gcur      = (int*)alloc(NB * 4);
  unsigned* featb = (unsigned*)alloc((size_t)NN * 64 * 4);        // reused as t-buffer
  unsigned short* A1e = (unsigned short*)alloc((size_t)100032 * ROWB);
  unsigned short* A2e = (unsigned short*)alloc((size_t)100032 * ROWB);
  unsigned short* W1e = (unsigned short*)alloc(128 * KEXT * 2);
  unsigned short* W2e = (unsigned short*)alloc(128 * KEXT * 2);
  float* stats   = (float*)alloc(512 * 4);
  float* scsh    = (float*)alloc(512 * 4);
  u64* stg       = (u64*)alloc((size_t)NE * 8);
  u64* fin       = (u64*)alloc((size_t)NE * 8);
  unsigned short* tbuf = (unsigned short*)featb;  // alias: featb dead after feg

  hipMemsetAsync(bcnt, 0, NB * 4, stream);
  hipMemsetAsync(stats, 0, 512 * 4, stream);
  hipMemsetAsync((char*)A1e + (size_t)NN * ROWB, 0, 32 * ROWB, stream);
  hipMemsetAsync((char*)A2e + (size_t)NN * ROWB, 0, 32 * ROWB, stream);

  wext_k<<<80, 256, 0, stream>>>(W1, Wb, bb, b1, W2, b2, W1e, W2e);
  featbf16_k<<<25000, 256, 0, stream>>>(features, featb);
  bhist_k<<<P1B, 256, 0, stream>>>(dst, bcnt);
  bscan_k<<<1, 1024, 0, stream>>>(bcnt, bbase, gcur, row_start);
  part_k<<<P1B, 256, 0, stream>>>(src, dst, gcur, stg);
  bsort_k<<<NB, 256, 0, stream>>>(stg, bbase, row_start, fin);
  feg_k<<<25000, 256, 0, stream>>>(featb, row_start, fin, edge_feats, A1e);

  gemm_mfma<false><<<1563, 256, 0, stream>>>(A1e, W1e, nullptr, tbuf,
                                             stats, stats + 128);
  bnfinal_k<<<1, 128, 0, stream>>>(stats, stats + 128, gamma1, beta1, scsh, scsh + 128);
  bn_apply_bf16<<<25000, 256, 0, stream>>>((const unsigned*)tbuf, scsh, scsh + 128, A2e);

  gemm_mfma<true><<<1563, 256, 0, stream>>>(A2e, W2e, features, tbuf,
                                            stats + 256, stats + 384);
  bnfinal_k<<<1, 128, 0, stream>>>(stats + 256, stats + 384, gamma2, beta2,
                                   scsh + 256, scsh + 384);
  bn_final_k<<<25000, 256, 0, stream>>>((const unsigned*)tbuf, scsh + 256, scsh + 384, outp);
}